// Round 1
// baseline (162.490 us; speedup 1.0000x reference)
//
#include <hip/hip_runtime.h>
#include <hip/hip_bf16.h>

#define NN 6144
#define IN_DIM 256
#define HID 64
#define HEADS 4
#define LAT 32
#define CAP 192
#define ALPHA 0.2f

__device__ __forceinline__ float elu_f(float v)   { return v > 0.f ? v : expm1f(v); }
__device__ __forceinline__ float lrelu_f(float v) { return v > 0.f ? v : ALPHA * v; }

// ---------------- scan A: neighbor lists + counts ----------------
__global__ __launch_bounds__(256) void k_scan(const float* __restrict__ A,
                                              int* __restrict__ nbr, int* __restrict__ cnt) {
    int row = blockIdx.x;
    const float4* Arow = (const float4*)(A + (size_t)row * NN);
    __shared__ int lcnt;
    if (threadIdx.x == 0) lcnt = 0;
    __syncthreads();
    int* my = nbr + (size_t)row * CAP;
    #pragma unroll
    for (int it = 0; it < NN / 4 / 256; ++it) {   // 6 iters
        int idx4 = it * 256 + threadIdx.x;
        float4 v = Arow[idx4];
        int base = idx4 * 4;
        if (v.x != 0.f) { int p = atomicAdd(&lcnt, 1); if (p < CAP) my[p] = base; }
        if (v.y != 0.f) { int p = atomicAdd(&lcnt, 1); if (p < CAP) my[p] = base + 1; }
        if (v.z != 0.f) { int p = atomicAdd(&lcnt, 1); if (p < CAP) my[p] = base + 2; }
        if (v.w != 0.f) { int p = atomicAdd(&lcnt, 1); if (p < CAP) my[p] = base + 3; }
    }
    __syncthreads();
    if (threadIdx.x == 0) cnt[row] = lcnt < CAP ? lcnt : CAP;
}

// ---------------- gemm1: Wh = x @ W_heads (per-head 64-col tiles) ----------------
__global__ __launch_bounds__(256) void k_gemm1(const float* __restrict__ x,
                                               const float* __restrict__ Wheads,
                                               float* __restrict__ Wh) {
    __shared__ float As[16][64];   // [k][m]
    __shared__ float Bs[16][64];   // [k][n]
    int m0 = blockIdx.x * 64;
    int head = blockIdx.y;
    const float* Wc = Wheads + (size_t)head * IN_DIM * HID;   // [256][64]
    int t = threadIdx.x;
    int ty = t >> 4, tx = t & 15;
    float acc[4][4] = {};
    for (int k0 = 0; k0 < IN_DIM; k0 += 16) {
        {
            int row = t >> 2, k4 = (t & 3) * 4;
            float4 v = *(const float4*)(x + (size_t)(m0 + row) * IN_DIM + k0 + k4);
            As[k4 + 0][row] = v.x; As[k4 + 1][row] = v.y;
            As[k4 + 2][row] = v.z; As[k4 + 3][row] = v.w;
            int kk = t >> 4, n4 = (t & 15) * 4;
            *(float4*)&Bs[kk][n4] = *(const float4*)(Wc + (size_t)(k0 + kk) * HID + n4);
        }
        __syncthreads();
        #pragma unroll
        for (int k = 0; k < 16; ++k) {
            float4 av = *(float4*)&As[k][ty * 4];
            float4 bv = *(float4*)&Bs[k][tx * 4];
            float ar[4] = {av.x, av.y, av.z, av.w};
            float br[4] = {bv.x, bv.y, bv.z, bv.w};
            #pragma unroll
            for (int i = 0; i < 4; ++i)
                #pragma unroll
                for (int j = 0; j < 4; ++j)
                    acc[i][j] = fmaf(ar[i], br[j], acc[i][j]);
        }
        __syncthreads();
    }
    #pragma unroll
    for (int i = 0; i < 4; ++i) {
        float4 o = make_float4(acc[i][0], acc[i][1], acc[i][2], acc[i][3]);
        *(float4*)(Wh + (size_t)(m0 + ty * 4 + i) * (HEADS * HID) + head * HID + tx * 4) = o;
    }
}

// ---------------- e_src/e_dst for layer 1 ----------------
__global__ __launch_bounds__(64) void k_esed1(const float* __restrict__ Wh,
                                              const float* __restrict__ aheads,
                                              float* __restrict__ es, float* __restrict__ ed) {
    int i = blockIdx.x, l = threadIdx.x;
    #pragma unroll
    for (int h = 0; h < HEADS; ++h) {
        float v = Wh[(size_t)i * (HEADS * HID) + h * HID + l];
        float p1 = v * aheads[h * 2 * HID + l];
        float p2 = v * aheads[h * 2 * HID + HID + l];
        #pragma unroll
        for (int off = 32; off; off >>= 1) { p1 += __shfl_down(p1, off); p2 += __shfl_down(p2, off); }
        if (l == 0) { es[h * NN + i] = p1; ed[h * NN + i] = p2; }
    }
}

// ---------------- column means (deg==0 fallback) ----------------
__global__ __launch_bounds__(256) void k_cm1(const float* __restrict__ Wh, float* __restrict__ cmean) {
    int c = threadIdx.x;
    float s = 0.f;
    int i0 = blockIdx.x * (NN / 64), i1 = i0 + (NN / 64);
    for (int i = i0; i < i1; ++i) s += Wh[(size_t)i * (HEADS * HID) + c];
    atomicAdd(&cmean[c], s * (1.0f / NN));
}
__global__ __launch_bounds__(64) void k_cm2(const float* __restrict__ Wh2, float* __restrict__ cm2v) {
    int c = threadIdx.x;
    if (c >= LAT) return;
    float s = 0.f;
    int i0 = blockIdx.x * (NN / 64), i1 = i0 + (NN / 64);
    for (int i = i0; i < i1; ++i) s += Wh2[(size_t)i * LAT + c];
    atomicAdd(&cm2v[c], s * (1.0f / NN));
}

// ---------------- attention layer 1 (one wave per row,head) ----------------
__global__ __launch_bounds__(64) void k_attn1(const int* __restrict__ nbr, const int* __restrict__ cnt,
                                              const float* __restrict__ es, const float* __restrict__ ed,
                                              const float* __restrict__ Wh, const float* __restrict__ cmean,
                                              float* __restrict__ hout) {
    __shared__ float att[CAP];
    __shared__ int col[CAP];
    int i = blockIdx.x, h = blockIdx.y, l = threadIdx.x;
    int c = cnt[i];
    if (c == 0) {
        hout[(size_t)i * (HEADS * HID) + h * HID + l] = elu_f(cmean[h * HID + l]);
        return;
    }
    float esi = es[h * NN + i];
    const int* nb = nbr + (size_t)i * CAP;
    float m = -3.0e38f;
    for (int j = l; j < c; j += 64) {
        int cj = nb[j];
        col[j] = cj;
        float e = lrelu_f(esi + ed[h * NN + cj]);
        att[j] = e;
        m = fmaxf(m, e);
    }
    #pragma unroll
    for (int off = 32; off; off >>= 1) m = fmaxf(m, __shfl_down(m, off));
    m = __shfl(m, 0);
    __syncthreads();
    float s = 0.f;
    for (int j = l; j < c; j += 64) {
        float p = __expf(att[j] - m);
        att[j] = p;
        s += p;
    }
    #pragma unroll
    for (int off = 32; off; off >>= 1) s += __shfl_down(s, off);
    s = __shfl(s, 0);
    __syncthreads();
    float inv = 1.0f / s;
    float acc = 0.f;
    for (int j = 0; j < c; ++j)
        acc = fmaf(att[j], Wh[(size_t)col[j] * (HEADS * HID) + h * HID + l], acc);
    acc *= inv;
    hout[(size_t)i * (HEADS * HID) + h * HID + l] = elu_f(acc);
}

// ---------------- gemm2: Wh2 = h @ W_out ----------------
__global__ __launch_bounds__(256) void k_gemm2(const float* __restrict__ hbuf,
                                               const float* __restrict__ Wout,
                                               float* __restrict__ Wh2) {
    __shared__ float hs[8][IN_DIM];
    int r0 = blockIdx.x * 8;
    int t = threadIdx.x;
    #pragma unroll
    for (int it = 0; it < 8; ++it) {
        int idx = it * 256 + t;
        hs[idx >> 8][idx & 255] = hbuf[(size_t)(r0 + (idx >> 8)) * IN_DIM + (idx & 255)];
    }
    __syncthreads();
    int r = t >> 5, cc = t & 31;
    float acc = 0.f;
    for (int k = 0; k < IN_DIM; ++k) acc = fmaf(hs[r][k], Wout[k * LAT + cc], acc);
    Wh2[(size_t)(r0 + r) * LAT + cc] = acc;
}

// ---------------- e2 ----------------
__global__ __launch_bounds__(64) void k_esed2(const float* __restrict__ Wh2,
                                              const float* __restrict__ aout,
                                              float* __restrict__ es2, float* __restrict__ ed2) {
    int i = blockIdx.x, l = threadIdx.x;
    float v  = (l < LAT) ? Wh2[(size_t)i * LAT + l] : 0.f;
    float p1 = (l < LAT) ? v * aout[l] : 0.f;
    float p2 = (l < LAT) ? v * aout[LAT + l] : 0.f;
    #pragma unroll
    for (int off = 32; off; off >>= 1) { p1 += __shfl_down(p1, off); p2 += __shfl_down(p2, off); }
    if (l == 0) { es2[i] = p1; ed2[i] = p2; }
}

// ---------------- attention layer 2 -> z ----------------
__global__ __launch_bounds__(64) void k_attn2(const int* __restrict__ nbr, const int* __restrict__ cnt,
                                              const float* __restrict__ es2, const float* __restrict__ ed2,
                                              const float* __restrict__ Wh2, const float* __restrict__ cm2v,
                                              float* __restrict__ z) {
    __shared__ float att[CAP];
    __shared__ int col[CAP];
    int i = blockIdx.x, l = threadIdx.x;
    int c = cnt[i];
    if (c == 0) {
        if (l < LAT) z[(size_t)i * LAT + l] = elu_f(cm2v[l]);
        return;
    }
    float esi = es2[i];
    const int* nb = nbr + (size_t)i * CAP;
    float m = -3.0e38f;
    for (int j = l; j < c; j += 64) {
        int cj = nb[j];
        col[j] = cj;
        float e = lrelu_f(esi + ed2[cj]);
        att[j] = e;
        m = fmaxf(m, e);
    }
    #pragma unroll
    for (int off = 32; off; off >>= 1) m = fmaxf(m, __shfl_down(m, off));
    m = __shfl(m, 0);
    __syncthreads();
    float s = 0.f;
    for (int j = l; j < c; j += 64) {
        float p = __expf(att[j] - m);
        att[j] = p;
        s += p;
    }
    #pragma unroll
    for (int off = 32; off; off >>= 1) s += __shfl_down(s, off);
    s = __shfl(s, 0);
    __syncthreads();
    if (l < LAT) {
        float inv = 1.0f / s;
        float acc = 0.f;
        for (int j = 0; j < c; ++j)
            acc = fmaf(att[j], Wh2[(size_t)col[j] * LAT + l], acc);
        z[(size_t)i * LAT + l] = elu_f(acc * inv);
    }
}

// ---------------- out = sigmoid(z @ z^T) ----------------
__global__ __launch_bounds__(256) void k_zzt(const float* __restrict__ z, float* __restrict__ out) {
    __shared__ float zr[LAT][64];   // [k][m]
    __shared__ float zc[LAT][64];   // [k][n]
    int m0 = blockIdx.y * 64, n0 = blockIdx.x * 64;
    int t = threadIdx.x;
    {
        int row = t >> 2, k8 = (t & 3) * 8;
        float4 v0 = *(const float4*)(z + (size_t)(m0 + row) * LAT + k8);
        float4 v1 = *(const float4*)(z + (size_t)(m0 + row) * LAT + k8 + 4);
        zr[k8 + 0][row] = v0.x; zr[k8 + 1][row] = v0.y; zr[k8 + 2][row] = v0.z; zr[k8 + 3][row] = v0.w;
        zr[k8 + 4][row] = v1.x; zr[k8 + 5][row] = v1.y; zr[k8 + 6][row] = v1.z; zr[k8 + 7][row] = v1.w;
        float4 u0 = *(const float4*)(z + (size_t)(n0 + row) * LAT + k8);
        float4 u1 = *(const float4*)(z + (size_t)(n0 + row) * LAT + k8 + 4);
        zc[k8 + 0][row] = u0.x; zc[k8 + 1][row] = u0.y; zc[k8 + 2][row] = u0.z; zc[k8 + 3][row] = u0.w;
        zc[k8 + 4][row] = u1.x; zc[k8 + 5][row] = u1.y; zc[k8 + 6][row] = u1.z; zc[k8 + 7][row] = u1.w;
    }
    __syncthreads();
    int ty = t >> 4, tx = t & 15;
    float acc[4][4] = {};
    #pragma unroll
    for (int k = 0; k < LAT; ++k) {
        float4 av = *(float4*)&zr[k][ty * 4];
        float4 bv = *(float4*)&zc[k][tx * 4];
        float ar[4] = {av.x, av.y, av.z, av.w};
        float br[4] = {bv.x, bv.y, bv.z, bv.w};
        #pragma unroll
        for (int i = 0; i < 4; ++i)
            #pragma unroll
            for (int j = 0; j < 4; ++j)
                acc[i][j] = fmaf(ar[i], br[j], acc[i][j]);
    }
    #pragma unroll
    for (int i = 0; i < 4; ++i) {
        float4 o;
        o.x = 1.0f / (1.0f + __expf(-acc[i][0]));
        o.y = 1.0f / (1.0f + __expf(-acc[i][1]));
        o.z = 1.0f / (1.0f + __expf(-acc[i][2]));
        o.w = 1.0f / (1.0f + __expf(-acc[i][3]));
        *(float4*)(out + (size_t)(m0 + ty * 4 + i) * NN + n0 + tx * 4) = o;
    }
}

extern "C" void kernel_launch(void* const* d_in, const int* in_sizes, int n_in,
                              void* d_out, int out_size, void* d_ws, size_t ws_size,
                              hipStream_t stream) {
    const float* x      = (const float*)d_in[0];
    const float* A      = (const float*)d_in[1];
    const float* Wheads = (const float*)d_in[2];
    const float* aheads = (const float*)d_in[3];
    const float* Wout   = (const float*)d_in[4];
    const float* aout   = (const float*)d_in[5];
    float* out = (float*)d_out;

    char* ws = (char*)d_ws;
    size_t o = 0;
    auto alloc = [&](size_t bytes) { void* p = ws + o; o += (bytes + 255) & ~(size_t)255; return p; };
    int*   nbr   = (int*)  alloc((size_t)NN * CAP * 4);
    int*   cnt   = (int*)  alloc((size_t)NN * 4);
    float* Wh    = (float*)alloc((size_t)NN * HEADS * HID * 4);
    float* es    = (float*)alloc((size_t)HEADS * NN * 4);
    float* ed    = (float*)alloc((size_t)HEADS * NN * 4);
    float* cm    = (float*)alloc(288 * 4);           // cmean(256) + cm2(32)
    float* hbuf  = (float*)alloc((size_t)NN * HEADS * HID * 4);
    float* Wh2   = (float*)alloc((size_t)NN * LAT * 4);
    float* es2   = (float*)alloc((size_t)NN * 4);
    float* ed2   = (float*)alloc((size_t)NN * 4);
    float* zbuf  = (float*)alloc((size_t)NN * LAT * 4);
    float* cmean = cm;
    float* cm2v  = cm + 256;

    hipMemsetAsync(cm, 0, 288 * 4, stream);
    k_scan  <<<NN, 256, 0, stream>>>(A, nbr, cnt);
    k_gemm1 <<<dim3(NN / 64, HEADS), 256, 0, stream>>>(x, Wheads, Wh);
    k_esed1 <<<NN, 64, 0, stream>>>(Wh, aheads, es, ed);
    k_cm1   <<<64, 256, 0, stream>>>(Wh, cmean);
    k_attn1 <<<dim3(NN, HEADS), 64, 0, stream>>>(nbr, cnt, es, ed, Wh, cmean, hbuf);
    k_gemm2 <<<NN / 8, 256, 0, stream>>>(hbuf, Wout, Wh2);
    k_esed2 <<<NN, 64, 0, stream>>>(Wh2, aout, es2, ed2);
    k_cm2   <<<64, 64, 0, stream>>>(Wh2, cm2v);
    k_attn2 <<<NN, 64, 0, stream>>>(nbr, cnt, es2, ed2, Wh2, cm2v, zbuf);
    k_zzt   <<<dim3(NN / 64, NN / 64), 256, 0, stream>>>(zbuf, out);
}

// Round 2
// 141.007 us; speedup vs baseline: 1.1524x; 1.1524x over previous
//
#include <hip/hip_runtime.h>
#include <hip/hip_bf16.h>

#define NN 6144
#define IN_DIM 256
#define HID 64
#define HEADS 4
#define LAT 32
#define CAP 192
#define ALPHA 0.2f

__device__ __forceinline__ float elu_f(float v)   { return v > 0.f ? v : expm1f(v); }
__device__ __forceinline__ float lrelu_f(float v) { return v > 0.f ? v : ALPHA * v; }

// ---------------- scan A: neighbor lists + counts ----------------
__global__ __launch_bounds__(256) void k_scan(const float* __restrict__ A,
                                              int* __restrict__ nbr, int* __restrict__ cnt) {
    int row = blockIdx.x;
    const float4* Arow = (const float4*)(A + (size_t)row * NN);
    __shared__ int lcnt;
    if (threadIdx.x == 0) lcnt = 0;
    __syncthreads();
    int* my = nbr + (size_t)row * CAP;
    #pragma unroll
    for (int it = 0; it < NN / 4 / 256; ++it) {   // 6 iters
        int idx4 = it * 256 + threadIdx.x;
        float4 v = Arow[idx4];
        int base = idx4 * 4;
        if (v.x != 0.f) { int p = atomicAdd(&lcnt, 1); if (p < CAP) my[p] = base; }
        if (v.y != 0.f) { int p = atomicAdd(&lcnt, 1); if (p < CAP) my[p] = base + 1; }
        if (v.z != 0.f) { int p = atomicAdd(&lcnt, 1); if (p < CAP) my[p] = base + 2; }
        if (v.w != 0.f) { int p = atomicAdd(&lcnt, 1); if (p < CAP) my[p] = base + 3; }
    }
    __syncthreads();
    if (threadIdx.x == 0) cnt[row] = lcnt < CAP ? lcnt : CAP;
}

// ---------------- gemm1: Wh = x @ W_heads, fused e_src/e_dst epilogue ----------------
__global__ __launch_bounds__(256) void k_gemm1f(const float* __restrict__ x,
                                                const float* __restrict__ Wheads,
                                                const float* __restrict__ aheads,
                                                float* __restrict__ Wh,
                                                float* __restrict__ es, float* __restrict__ ed) {
    __shared__ float As[16][64];   // [k][m]
    __shared__ float Bs[16][64];   // [k][n]
    int m0 = blockIdx.x * 64;
    int head = blockIdx.y;
    const float* Wc = Wheads + (size_t)head * IN_DIM * HID;   // [256][64]
    int t = threadIdx.x;
    int ty = t >> 4, tx = t & 15;
    float acc[4][4] = {};
    for (int k0 = 0; k0 < IN_DIM; k0 += 16) {
        {
            int row = t >> 2, k4 = (t & 3) * 4;
            float4 v = *(const float4*)(x + (size_t)(m0 + row) * IN_DIM + k0 + k4);
            As[k4 + 0][row] = v.x; As[k4 + 1][row] = v.y;
            As[k4 + 2][row] = v.z; As[k4 + 3][row] = v.w;
            int kk = t >> 4, n4 = (t & 15) * 4;
            *(float4*)&Bs[kk][n4] = *(const float4*)(Wc + (size_t)(k0 + kk) * HID + n4);
        }
        __syncthreads();
        #pragma unroll
        for (int k = 0; k < 16; ++k) {
            float4 av = *(float4*)&As[k][ty * 4];
            float4 bv = *(float4*)&Bs[k][tx * 4];
            float ar[4] = {av.x, av.y, av.z, av.w};
            float br[4] = {bv.x, bv.y, bv.z, bv.w};
            #pragma unroll
            for (int i = 0; i < 4; ++i)
                #pragma unroll
                for (int j = 0; j < 4; ++j)
                    acc[i][j] = fmaf(ar[i], br[j], acc[i][j]);
        }
        __syncthreads();
    }
    #pragma unroll
    for (int i = 0; i < 4; ++i) {
        float4 o = make_float4(acc[i][0], acc[i][1], acc[i][2], acc[i][3]);
        *(float4*)(Wh + (size_t)(m0 + ty * 4 + i) * (HEADS * HID) + head * HID + tx * 4) = o;
    }
    // epilogue: e_src = Wh . a[:64], e_dst = Wh . a[64:] (reduce over tx groups)
    float4 a1v = *(const float4*)(aheads + head * 2 * HID + tx * 4);
    float4 a2v = *(const float4*)(aheads + head * 2 * HID + HID + tx * 4);
    #pragma unroll
    for (int i = 0; i < 4; ++i) {
        float p1 = acc[i][0] * a1v.x + acc[i][1] * a1v.y + acc[i][2] * a1v.z + acc[i][3] * a1v.w;
        float p2 = acc[i][0] * a2v.x + acc[i][1] * a2v.y + acc[i][2] * a2v.z + acc[i][3] * a2v.w;
        #pragma unroll
        for (int off = 8; off; off >>= 1) {
            p1 += __shfl_down(p1, off, 16);
            p2 += __shfl_down(p2, off, 16);
        }
        if (tx == 0) {
            es[head * NN + m0 + ty * 4 + i] = p1;
            ed[head * NN + m0 + ty * 4 + i] = p2;
        }
    }
}

// ---------------- attention layer 1 (one wave per row,head) ----------------
__global__ __launch_bounds__(64) void k_attn1(const int* __restrict__ nbr, const int* __restrict__ cnt,
                                              const float* __restrict__ es, const float* __restrict__ ed,
                                              const float* __restrict__ Wh,
                                              float* __restrict__ hout) {
    __shared__ float att[CAP];
    __shared__ int col[CAP];
    int i = blockIdx.x, h = blockIdx.y, l = threadIdx.x;
    int c = cnt[i];
    if (c == 0) {   // deg==0: softmax over all-NEG_INF row -> uniform -> column mean
        float s = 0.f;
        for (int r = 0; r < NN; ++r) s += Wh[(size_t)r * (HEADS * HID) + h * HID + l];
        hout[(size_t)i * (HEADS * HID) + h * HID + l] = elu_f(s * (1.0f / NN));
        return;
    }
    float esi = es[h * NN + i];
    const int* nb = nbr + (size_t)i * CAP;
    float m = -3.0e38f;
    for (int j = l; j < c; j += 64) {
        int cj = nb[j];
        col[j] = cj;
        float e = lrelu_f(esi + ed[h * NN + cj]);
        att[j] = e;
        m = fmaxf(m, e);
    }
    #pragma unroll
    for (int off = 32; off; off >>= 1) m = fmaxf(m, __shfl_down(m, off));
    m = __shfl(m, 0);
    __syncthreads();
    float s = 0.f;
    for (int j = l; j < c; j += 64) {
        float p = __expf(att[j] - m);
        att[j] = p;
        s += p;
    }
    #pragma unroll
    for (int off = 32; off; off >>= 1) s += __shfl_down(s, off);
    s = __shfl(s, 0);
    __syncthreads();
    float inv = 1.0f / s;
    float acc = 0.f;
    for (int j = 0; j < c; ++j)
        acc = fmaf(att[j], Wh[(size_t)col[j] * (HEADS * HID) + h * HID + l], acc);
    acc *= inv;
    hout[(size_t)i * (HEADS * HID) + h * HID + l] = elu_f(acc);
}

// ---------------- gemm2: Wh2 = h @ W_out, fused e2 epilogue ----------------
__global__ __launch_bounds__(256) void k_gemm2f(const float* __restrict__ hbuf,
                                                const float* __restrict__ Wout,
                                                const float* __restrict__ aout,
                                                float* __restrict__ Wh2,
                                                float* __restrict__ es2, float* __restrict__ ed2) {
    __shared__ float hs[8][IN_DIM];          // 8 KB
    __shared__ float ws_lds[IN_DIM][LAT];    // 32 KB
    int r0 = blockIdx.x * 8;
    int t = threadIdx.x;
    #pragma unroll
    for (int it = 0; it < 8; ++it) {
        int idx = it * 256 + t;
        hs[idx >> 8][idx & 255] = hbuf[(size_t)(r0 + (idx >> 8)) * IN_DIM + (idx & 255)];
    }
    #pragma unroll
    for (int it = 0; it < 8; ++it) {   // 8192 floats = 2048 float4
        int q = it * 256 + t;          // float4 index
        *(float4*)&ws_lds[0][0 + q * 4] = *(const float4*)(Wout + q * 4);
    }
    __syncthreads();
    int r = t >> 5, cc = t & 31;
    float acc = 0.f;
    for (int k = 0; k < IN_DIM; ++k) acc = fmaf(hs[r][k], ws_lds[k][cc], acc);
    Wh2[(size_t)(r0 + r) * LAT + cc] = acc;
    // epilogue: e_src2/e_dst2
    float p1 = acc * aout[cc];
    float p2 = acc * aout[LAT + cc];
    #pragma unroll
    for (int off = 16; off; off >>= 1) {
        p1 += __shfl_down(p1, off, 32);
        p2 += __shfl_down(p2, off, 32);
    }
    if (cc == 0) { es2[r0 + r] = p1; ed2[r0 + r] = p2; }
}

// ---------------- attention layer 2 -> z ----------------
__global__ __launch_bounds__(64) void k_attn2(const int* __restrict__ nbr, const int* __restrict__ cnt,
                                              const float* __restrict__ es2, const float* __restrict__ ed2,
                                              const float* __restrict__ Wh2,
                                              float* __restrict__ z) {
    __shared__ float att[CAP];
    __shared__ int col[CAP];
    int i = blockIdx.x, l = threadIdx.x;
    int c = cnt[i];
    if (c == 0) {
        if (l < LAT) {
            float s = 0.f;
            for (int r = 0; r < NN; ++r) s += Wh2[(size_t)r * LAT + l];
            z[(size_t)i * LAT + l] = elu_f(s * (1.0f / NN));
        }
        return;
    }
    float esi = es2[i];
    const int* nb = nbr + (size_t)i * CAP;
    float m = -3.0e38f;
    for (int j = l; j < c; j += 64) {
        int cj = nb[j];
        col[j] = cj;
        float e = lrelu_f(esi + ed2[cj]);
        att[j] = e;
        m = fmaxf(m, e);
    }
    #pragma unroll
    for (int off = 32; off; off >>= 1) m = fmaxf(m, __shfl_down(m, off));
    m = __shfl(m, 0);
    __syncthreads();
    float s = 0.f;
    for (int j = l; j < c; j += 64) {
        float p = __expf(att[j] - m);
        att[j] = p;
        s += p;
    }
    #pragma unroll
    for (int off = 32; off; off >>= 1) s += __shfl_down(s, off);
    s = __shfl(s, 0);
    __syncthreads();
    if (l < LAT) {
        float inv = 1.0f / s;
        float acc = 0.f;
        for (int j = 0; j < c; ++j)
            acc = fmaf(att[j], Wh2[(size_t)col[j] * LAT + l], acc);
        z[(size_t)i * LAT + l] = elu_f(acc * inv);
    }
}

// ---------------- out = sigmoid(z @ z^T), 128x128 tile, 8x8/thread ----------------
__global__ __launch_bounds__(256) void k_zzt(const float* __restrict__ z, float* __restrict__ out) {
    __shared__ float zr[LAT][128];   // [k][m]
    __shared__ float zc[LAT][128];   // [k][n]
    int m0 = blockIdx.y * 128, n0 = blockIdx.x * 128;
    int t = threadIdx.x;
    // load 128 rows x 32 k per side; 1024 float4-chunks per side, 4 per thread
    #pragma unroll
    for (int it = 0; it < 4; ++it) {
        int chunk = it * 256 + t;
        int row = chunk >> 3, k4 = (chunk & 7) * 4;
        float4 v = *(const float4*)(z + (size_t)(m0 + row) * LAT + k4);
        zr[k4 + 0][row] = v.x; zr[k4 + 1][row] = v.y; zr[k4 + 2][row] = v.z; zr[k4 + 3][row] = v.w;
        float4 u = *(const float4*)(z + (size_t)(n0 + row) * LAT + k4);
        zc[k4 + 0][row] = u.x; zc[k4 + 1][row] = u.y; zc[k4 + 2][row] = u.z; zc[k4 + 3][row] = u.w;
    }
    __syncthreads();
    int ty = t >> 4, tx = t & 15;
    // thread computes rows {ty*4+i, 64+ty*4+i} x cols {tx*4+j, 64+tx*4+j}
    float acc[2][2][4][4] = {};
    #pragma unroll 4
    for (int k = 0; k < LAT; ++k) {
        float4 a0 = *(float4*)&zr[k][ty * 4];
        float4 a1 = *(float4*)&zr[k][64 + ty * 4];
        float4 b0 = *(float4*)&zc[k][tx * 4];
        float4 b1 = *(float4*)&zc[k][64 + tx * 4];
        float ar[2][4] = {{a0.x, a0.y, a0.z, a0.w}, {a1.x, a1.y, a1.z, a1.w}};
        float br[2][4] = {{b0.x, b0.y, b0.z, b0.w}, {b1.x, b1.y, b1.z, b1.w}};
        #pragma unroll
        for (int p = 0; p < 2; ++p)
            #pragma unroll
            for (int q = 0; q < 2; ++q)
                #pragma unroll
                for (int i = 0; i < 4; ++i)
                    #pragma unroll
                    for (int j = 0; j < 4; ++j)
                        acc[p][q][i][j] = fmaf(ar[p][i], br[q][j], acc[p][q][i][j]);
    }
    #pragma unroll
    for (int p = 0; p < 2; ++p) {
        #pragma unroll
        for (int i = 0; i < 4; ++i) {
            int row = m0 + p * 64 + ty * 4 + i;
            #pragma unroll
            for (int q = 0; q < 2; ++q) {
                float4 o;
                o.x = 1.0f / (1.0f + __expf(-acc[p][q][i][0]));
                o.y = 1.0f / (1.0f + __expf(-acc[p][q][i][1]));
                o.z = 1.0f / (1.0f + __expf(-acc[p][q][i][2]));
                o.w = 1.0f / (1.0f + __expf(-acc[p][q][i][3]));
                *(float4*)(out + (size_t)row * NN + n0 + q * 64 + tx * 4) = o;
            }
        }
    }
}

extern "C" void kernel_launch(void* const* d_in, const int* in_sizes, int n_in,
                              void* d_out, int out_size, void* d_ws, size_t ws_size,
                              hipStream_t stream) {
    const float* x      = (const float*)d_in[0];
    const float* A      = (const float*)d_in[1];
    const float* Wheads = (const float*)d_in[2];
    const float* aheads = (const float*)d_in[3];
    const float* Wout   = (const float*)d_in[4];
    const float* aout   = (const float*)d_in[5];
    float* out = (float*)d_out;

    char* ws = (char*)d_ws;
    size_t o = 0;
    auto alloc = [&](size_t bytes) { void* p = ws + o; o += (bytes + 255) & ~(size_t)255; return p; };
    int*   nbr   = (int*)  alloc((size_t)NN * CAP * 4);
    int*   cnt   = (int*)  alloc((size_t)NN * 4);
    float* Wh    = (float*)alloc((size_t)NN * HEADS * HID * 4);
    float* es    = (float*)alloc((size_t)HEADS * NN * 4);
    float* ed    = (float*)alloc((size_t)HEADS * NN * 4);
    float* hbuf  = (float*)alloc((size_t)NN * HEADS * HID * 4);
    float* Wh2   = (float*)alloc((size_t)NN * LAT * 4);
    float* es2   = (float*)alloc((size_t)NN * 4);
    float* ed2   = (float*)alloc((size_t)NN * 4);
    float* zbuf  = (float*)alloc((size_t)NN * LAT * 4);

    k_scan   <<<NN, 256, 0, stream>>>(A, nbr, cnt);
    k_gemm1f <<<dim3(NN / 64, HEADS), 256, 0, stream>>>(x, Wheads, aheads, Wh, es, ed);
    k_attn1  <<<dim3(NN, HEADS), 64, 0, stream>>>(nbr, cnt, es, ed, Wh, hbuf);
    k_gemm2f <<<NN / 8, 256, 0, stream>>>(hbuf, Wout, aout, Wh2, es2, ed2);
    k_attn2  <<<NN, 64, 0, stream>>>(nbr, cnt, es2, ed2, Wh2, zbuf);
    k_zzt    <<<dim3(NN / 128, NN / 128), 256, 0, stream>>>(zbuf, out);
}

// Round 3
// 127.131 us; speedup vs baseline: 1.2781x; 1.1092x over previous
//
#include <hip/hip_runtime.h>
#include <hip/hip_bf16.h>

#define NN 6144
#define IN_DIM 256
#define HID 64
#define HEADS 4
#define LAT 32
#define CAP 192
#define ALPHA 0.2f
#define GEMM_BLOCKS 384   // (NN/64) * HEADS

__device__ __forceinline__ float elu_f(float v)   { return v > 0.f ? v : expm1f(v); }
__device__ __forceinline__ float lrelu_f(float v) { return v > 0.f ? v : ALPHA * v; }

// ---------------- k_pre: gemm1(+e_src/e_dst epilogue) blocks first, then A-scan blocks ----------------
__global__ __launch_bounds__(256) void k_pre(const float* __restrict__ A,
                                             const float* __restrict__ x,
                                             const float* __restrict__ Wheads,
                                             const float* __restrict__ aheads,
                                             int* __restrict__ nbr, int* __restrict__ cnt,
                                             float* __restrict__ Wh,
                                             float* __restrict__ es, float* __restrict__ ed) {
    __shared__ __align__(16) float smem[2048];   // 8 KB
    int bid = blockIdx.x;
    int t = threadIdx.x;
    if (bid < GEMM_BLOCKS) {
        // ---- gemm1 fused: Wh = x @ W_heads[head], es/ed epilogue ----
        int head = bid & 3, m0 = (bid >> 2) * 64;
        float (*As)[64] = (float(*)[64])smem;            // [16][64]
        float (*Bs)[64] = (float(*)[64])(smem + 1024);   // [16][64]
        const float* Wc = Wheads + (size_t)head * IN_DIM * HID;
        int ty = t >> 4, tx = t & 15;
        float acc[4][4] = {};
        for (int k0 = 0; k0 < IN_DIM; k0 += 16) {
            {
                int row = t >> 2, k4 = (t & 3) * 4;
                float4 v = *(const float4*)(x + (size_t)(m0 + row) * IN_DIM + k0 + k4);
                As[k4 + 0][row] = v.x; As[k4 + 1][row] = v.y;
                As[k4 + 2][row] = v.z; As[k4 + 3][row] = v.w;
                int kk = t >> 4, n4 = (t & 15) * 4;
                *(float4*)&Bs[kk][n4] = *(const float4*)(Wc + (size_t)(k0 + kk) * HID + n4);
            }
            __syncthreads();
            #pragma unroll
            for (int k = 0; k < 16; ++k) {
                float4 av = *(float4*)&As[k][ty * 4];
                float4 bv = *(float4*)&Bs[k][tx * 4];
                float ar[4] = {av.x, av.y, av.z, av.w};
                float br[4] = {bv.x, bv.y, bv.z, bv.w};
                #pragma unroll
                for (int i = 0; i < 4; ++i)
                    #pragma unroll
                    for (int j = 0; j < 4; ++j)
                        acc[i][j] = fmaf(ar[i], br[j], acc[i][j]);
            }
            __syncthreads();
        }
        #pragma unroll
        for (int i = 0; i < 4; ++i) {
            float4 o = make_float4(acc[i][0], acc[i][1], acc[i][2], acc[i][3]);
            *(float4*)(Wh + (size_t)(m0 + ty * 4 + i) * (HEADS * HID) + head * HID + tx * 4) = o;
        }
        float4 a1v = *(const float4*)(aheads + head * 2 * HID + tx * 4);
        float4 a2v = *(const float4*)(aheads + head * 2 * HID + HID + tx * 4);
        #pragma unroll
        for (int i = 0; i < 4; ++i) {
            float p1 = acc[i][0] * a1v.x + acc[i][1] * a1v.y + acc[i][2] * a1v.z + acc[i][3] * a1v.w;
            float p2 = acc[i][0] * a2v.x + acc[i][1] * a2v.y + acc[i][2] * a2v.z + acc[i][3] * a2v.w;
            #pragma unroll
            for (int off = 8; off; off >>= 1) {
                p1 += __shfl_down(p1, off, 16);
                p2 += __shfl_down(p2, off, 16);
            }
            if (tx == 0) {
                es[head * NN + m0 + ty * 4 + i] = p1;
                ed[head * NN + m0 + ty * 4 + i] = p2;
            }
        }
    } else {
        // ---- scan row of A -> neighbor list ----
        int row = bid - GEMM_BLOCKS;
        int* lcnt = (int*)smem;
        const float4* Arow = (const float4*)(A + (size_t)row * NN);
        if (t == 0) *lcnt = 0;
        __syncthreads();
        int* my = nbr + (size_t)row * CAP;
        #pragma unroll
        for (int it = 0; it < NN / 4 / 256; ++it) {
            int idx4 = it * 256 + t;
            float4 v = Arow[idx4];
            int base = idx4 * 4;
            if (v.x != 0.f) { int p = atomicAdd(lcnt, 1); if (p < CAP) my[p] = base; }
            if (v.y != 0.f) { int p = atomicAdd(lcnt, 1); if (p < CAP) my[p] = base + 1; }
            if (v.z != 0.f) { int p = atomicAdd(lcnt, 1); if (p < CAP) my[p] = base + 2; }
            if (v.w != 0.f) { int p = atomicAdd(lcnt, 1); if (p < CAP) my[p] = base + 3; }
        }
        __syncthreads();
        if (t == 0) cnt[row] = *lcnt < CAP ? *lcnt : CAP;
    }
}

// ---------------- k_attn1g2: attention layer 1 (4 waves = 4 heads per row) + fused gemm2/e2 ----------------
__global__ __launch_bounds__(256) void k_attn1g2(const int* __restrict__ nbr, const int* __restrict__ cnt,
                                                 const float* __restrict__ es, const float* __restrict__ ed,
                                                 const float* __restrict__ Wh,
                                                 const float* __restrict__ Wout, const float* __restrict__ aout,
                                                 float* __restrict__ Wh2,
                                                 float* __restrict__ es2, float* __restrict__ ed2) {
    __shared__ int col[CAP];
    __shared__ float att[HEADS][CAP];
    __shared__ float hrow[HEADS * HID];
    __shared__ float part[8][LAT];
    int i = blockIdx.x;
    int t = threadIdx.x, h = t >> 6, l = t & 63;
    int c = cnt[i];
    float hval;
    if (c == 0) {   // deg==0: uniform softmax -> column mean (never taken w.h.p., kept for correctness)
        float s = 0.f;
        for (int r = 0; r < NN; ++r) s += Wh[(size_t)r * (HEADS * HID) + h * HID + l];
        hval = elu_f(s * (1.0f / NN));
    } else {
        const int* nb = nbr + (size_t)i * CAP;
        float esi = es[h * NN + i];
        float m = -3.0e38f;
        for (int j = l; j < c; j += 64) {
            int cj = nb[j];
            if (h == 0) col[j] = cj;
            float e = lrelu_f(esi + ed[h * NN + cj]);
            att[h][j] = e;
            m = fmaxf(m, e);
        }
        #pragma unroll
        for (int off = 32; off; off >>= 1) m = fmaxf(m, __shfl_down(m, off));
        m = __shfl(m, 0);
        float s = 0.f;
        for (int j = l; j < c; j += 64) {
            float p = __expf(att[h][j] - m);
            att[h][j] = p;
            s += p;
        }
        #pragma unroll
        for (int off = 32; off; off >>= 1) s += __shfl_down(s, off);
        s = __shfl(s, 0);
        __syncthreads();          // col[] + att[h][] visible to all
        float inv = 1.0f / s;
        const float* WhH = Wh + h * HID + l;
        float acc0 = 0.f, acc1 = 0.f, acc2 = 0.f, acc3 = 0.f;
        int j = 0;
        for (; j + 4 <= c; j += 4) {
            acc0 = fmaf(att[h][j + 0], WhH[(size_t)col[j + 0] * (HEADS * HID)], acc0);
            acc1 = fmaf(att[h][j + 1], WhH[(size_t)col[j + 1] * (HEADS * HID)], acc1);
            acc2 = fmaf(att[h][j + 2], WhH[(size_t)col[j + 2] * (HEADS * HID)], acc2);
            acc3 = fmaf(att[h][j + 3], WhH[(size_t)col[j + 3] * (HEADS * HID)], acc3);
        }
        for (; j < c; ++j)
            acc0 = fmaf(att[h][j], WhH[(size_t)col[j] * (HEADS * HID)], acc0);
        hval = elu_f(((acc0 + acc1) + (acc2 + acc3)) * inv);
    }
    hrow[h * HID + l] = hval;
    __syncthreads();
    // gemm2: wave h covers input dims [h*64, h*64+64), split into 2 halves of 32; 32 output cols
    {
        int half = l >> 5, cc = l & 31;
        int tbase = h * HID + half * 32;
        float p = 0.f;
        #pragma unroll 8
        for (int tt = 0; tt < 32; ++tt)
            p = fmaf(hrow[tbase + tt], Wout[(tbase + tt) * LAT + cc], p);
        part[h * 2 + half][cc] = p;
    }
    __syncthreads();
    if (t < 32) {
        float acc = 0.f;
        #pragma unroll
        for (int w = 0; w < 8; ++w) acc += part[w][t];
        Wh2[(size_t)i * LAT + t] = acc;
        float p1 = acc * aout[t], p2 = acc * aout[LAT + t];
        #pragma unroll
        for (int off = 16; off; off >>= 1) {
            p1 += __shfl_down(p1, off, 32);
            p2 += __shfl_down(p2, off, 32);
        }
        if (t == 0) { es2[i] = p1; ed2[i] = p2; }
    }
}

// ---------------- attention layer 2 -> z (4 rows per block, wave per row) ----------------
__global__ __launch_bounds__(256) void k_attn2(const int* __restrict__ nbr, const int* __restrict__ cnt,
                                               const float* __restrict__ es2, const float* __restrict__ ed2,
                                               const float* __restrict__ Wh2,
                                               float* __restrict__ z) {
    __shared__ float att[4][CAP];
    __shared__ int col[4][CAP];
    int w = threadIdx.x >> 6, l = threadIdx.x & 63;
    int i = blockIdx.x * 4 + w;
    int c = cnt[i];
    if (c == 0) {
        if (l < LAT) {
            float s = 0.f;
            for (int r = 0; r < NN; ++r) s += Wh2[(size_t)r * LAT + l];
            z[(size_t)i * LAT + l] = elu_f(s * (1.0f / NN));
        }
        return;
    }
    float esi = es2[i];
    const int* nb = nbr + (size_t)i * CAP;
    float m = -3.0e38f;
    for (int j = l; j < c; j += 64) {
        int cj = nb[j];
        col[w][j] = cj;
        float e = lrelu_f(esi + ed2[cj]);
        att[w][j] = e;
        m = fmaxf(m, e);
    }
    #pragma unroll
    for (int off = 32; off; off >>= 1) m = fmaxf(m, __shfl_down(m, off));
    m = __shfl(m, 0);
    float s = 0.f;
    for (int j = l; j < c; j += 64) {
        float p = __expf(att[w][j] - m);
        att[w][j] = p;
        s += p;
    }
    #pragma unroll
    for (int off = 32; off; off >>= 1) s += __shfl_down(s, off);
    s = __shfl(s, 0);
    if (l < LAT) {
        float inv = 1.0f / s;
        float acc0 = 0.f, acc1 = 0.f, acc2 = 0.f, acc3 = 0.f;
        int j = 0;
        for (; j + 4 <= c; j += 4) {
            acc0 = fmaf(att[w][j + 0], Wh2[(size_t)col[w][j + 0] * LAT + l], acc0);
            acc1 = fmaf(att[w][j + 1], Wh2[(size_t)col[w][j + 1] * LAT + l], acc1);
            acc2 = fmaf(att[w][j + 2], Wh2[(size_t)col[w][j + 2] * LAT + l], acc2);
            acc3 = fmaf(att[w][j + 3], Wh2[(size_t)col[w][j + 3] * LAT + l], acc3);
        }
        for (; j < c; ++j)
            acc0 = fmaf(att[w][j], Wh2[(size_t)col[w][j] * LAT + l], acc0);
        z[(size_t)i * LAT + l] = elu_f(((acc0 + acc1) + (acc2 + acc3)) * inv);
    }
}

// ---------------- out = sigmoid(z @ z^T), 128x128 tile, 8x8/thread ----------------
__global__ __launch_bounds__(256) void k_zzt(const float* __restrict__ z, float* __restrict__ out) {
    __shared__ float zr[LAT][128];   // [k][m]
    __shared__ float zc[LAT][128];   // [k][n]
    int m0 = blockIdx.y * 128, n0 = blockIdx.x * 128;
    int t = threadIdx.x;
    #pragma unroll
    for (int it = 0; it < 4; ++it) {
        int chunk = it * 256 + t;
        int row = chunk >> 3, k4 = (chunk & 7) * 4;
        float4 v = *(const float4*)(z + (size_t)(m0 + row) * LAT + k4);
        zr[k4 + 0][row] = v.x; zr[k4 + 1][row] = v.y; zr[k4 + 2][row] = v.z; zr[k4 + 3][row] = v.w;
        float4 u = *(const float4*)(z + (size_t)(n0 + row) * LAT + k4);
        zc[k4 + 0][row] = u.x; zc[k4 + 1][row] = u.y; zc[k4 + 2][row] = u.z; zc[k4 + 3][row] = u.w;
    }
    __syncthreads();
    int ty = t >> 4, tx = t & 15;
    float acc[2][2][4][4] = {};
    #pragma unroll 4
    for (int k = 0; k < LAT; ++k) {
        float4 a0 = *(float4*)&zr[k][ty * 4];
        float4 a1 = *(float4*)&zr[k][64 + ty * 4];
        float4 b0 = *(float4*)&zc[k][tx * 4];
        float4 b1 = *(float4*)&zc[k][64 + tx * 4];
        float ar[2][4] = {{a0.x, a0.y, a0.z, a0.w}, {a1.x, a1.y, a1.z, a1.w}};
        float br[2][4] = {{b0.x, b0.y, b0.z, b0.w}, {b1.x, b1.y, b1.z, b1.w}};
        #pragma unroll
        for (int p = 0; p < 2; ++p)
            #pragma unroll
            for (int q = 0; q < 2; ++q)
                #pragma unroll
                for (int i = 0; i < 4; ++i)
                    #pragma unroll
                    for (int j = 0; j < 4; ++j)
                        acc[p][q][i][j] = fmaf(ar[p][i], br[q][j], acc[p][q][i][j]);
    }
    #pragma unroll
    for (int p = 0; p < 2; ++p) {
        #pragma unroll
        for (int i = 0; i < 4; ++i) {
            int row = m0 + p * 64 + ty * 4 + i;
            #pragma unroll
            for (int q = 0; q < 2; ++q) {
                float4 o;
                o.x = 1.0f / (1.0f + __expf(-acc[p][q][i][0]));
                o.y = 1.0f / (1.0f + __expf(-acc[p][q][i][1]));
                o.z = 1.0f / (1.0f + __expf(-acc[p][q][i][2]));
                o.w = 1.0f / (1.0f + __expf(-acc[p][q][i][3]));
                *(float4*)(out + (size_t)row * NN + n0 + q * 64 + tx * 4) = o;
            }
        }
    }
}

extern "C" void kernel_launch(void* const* d_in, const int* in_sizes, int n_in,
                              void* d_out, int out_size, void* d_ws, size_t ws_size,
                              hipStream_t stream) {
    const float* x      = (const float*)d_in[0];
    const float* A      = (const float*)d_in[1];
    const float* Wheads = (const float*)d_in[2];
    const float* aheads = (const float*)d_in[3];
    const float* Wout   = (const float*)d_in[4];
    const float* aout   = (const float*)d_in[5];
    float* out = (float*)d_out;

    char* ws = (char*)d_ws;
    size_t o = 0;
    auto alloc = [&](size_t bytes) { void* p = ws + o; o += (bytes + 255) & ~(size_t)255; return p; };
    int*   nbr   = (int*)  alloc((size_t)NN * CAP * 4);
    int*   cnt   = (int*)  alloc((size_t)NN * 4);
    float* Wh    = (float*)alloc((size_t)NN * HEADS * HID * 4);
    float* es    = (float*)alloc((size_t)HEADS * NN * 4);
    float* ed    = (float*)alloc((size_t)HEADS * NN * 4);
    float* Wh2   = (float*)alloc((size_t)NN * LAT * 4);
    float* es2   = (float*)alloc((size_t)NN * 4);
    float* ed2   = (float*)alloc((size_t)NN * 4);
    float* zbuf  = (float*)alloc((size_t)NN * LAT * 4);

    k_pre     <<<GEMM_BLOCKS + NN, 256, 0, stream>>>(A, x, Wheads, aheads, nbr, cnt, Wh, es, ed);
    k_attn1g2 <<<NN, 256, 0, stream>>>(nbr, cnt, es, ed, Wh, Wout, aout, Wh2, es2, ed2);
    k_attn2   <<<NN / 4, 256, 0, stream>>>(nbr, cnt, es2, ed2, Wh2, zbuf);
    k_zzt     <<<dim3(NN / 128, NN / 128), 256, 0, stream>>>(zbuf, out);
}

// Round 4
// 114.939 us; speedup vs baseline: 1.4137x; 1.1061x over previous
//
#include <hip/hip_runtime.h>
#include <hip/hip_bf16.h>

#define NN 6144
#define IN_DIM 256
#define HID 64
#define HEADS 4
#define LAT 32
#define CAP 192
#define ALPHA 0.2f
#define GEMM_BLOCKS 384   // (NN/64) * HEADS

typedef __attribute__((ext_vector_type(8))) short bf16x8;
typedef __attribute__((ext_vector_type(4))) float f32x4;

__device__ __forceinline__ float elu_f(float v)   { return v > 0.f ? v : expm1f(v); }
__device__ __forceinline__ float lrelu_f(float v) { return v > 0.f ? v : ALPHA * v; }

__device__ __forceinline__ void split_bf16(float v, unsigned short& hi, unsigned short& lo) {
    unsigned u = __builtin_bit_cast(unsigned, v);
    hi = (unsigned short)(u >> 16);
    float vh = __builtin_bit_cast(float, u & 0xFFFF0000u);
    float rl = v - vh;                       // exact
    lo = (unsigned short)(__builtin_bit_cast(unsigned, rl) >> 16);
}

// ---------------- k_pre: gemm1(+e_src/e_dst epilogue) blocks first, then A-scan blocks ----------------
__global__ __launch_bounds__(256) void k_pre(const float* __restrict__ A,
                                             const float* __restrict__ x,
                                             const float* __restrict__ Wheads,
                                             const float* __restrict__ aheads,
                                             int* __restrict__ nbr, int* __restrict__ cnt,
                                             float* __restrict__ Wh,
                                             float* __restrict__ es, float* __restrict__ ed) {
    __shared__ __align__(16) float smem[2048];   // 8 KB
    int bid = blockIdx.x;
    int t = threadIdx.x;
    if (bid < GEMM_BLOCKS) {
        int head = bid & 3, m0 = (bid >> 2) * 64;
        float (*As)[64] = (float(*)[64])smem;
        float (*Bs)[64] = (float(*)[64])(smem + 1024);
        const float* Wc = Wheads + (size_t)head * IN_DIM * HID;
        int ty = t >> 4, tx = t & 15;
        float acc[4][4] = {};
        for (int k0 = 0; k0 < IN_DIM; k0 += 16) {
            {
                int row = t >> 2, k4 = (t & 3) * 4;
                float4 v = *(const float4*)(x + (size_t)(m0 + row) * IN_DIM + k0 + k4);
                As[k4 + 0][row] = v.x; As[k4 + 1][row] = v.y;
                As[k4 + 2][row] = v.z; As[k4 + 3][row] = v.w;
                int kk = t >> 4, n4 = (t & 15) * 4;
                *(float4*)&Bs[kk][n4] = *(const float4*)(Wc + (size_t)(k0 + kk) * HID + n4);
            }
            __syncthreads();
            #pragma unroll
            for (int k = 0; k < 16; ++k) {
                float4 av = *(float4*)&As[k][ty * 4];
                float4 bv = *(float4*)&Bs[k][tx * 4];
                float ar[4] = {av.x, av.y, av.z, av.w};
                float br[4] = {bv.x, bv.y, bv.z, bv.w};
                #pragma unroll
                for (int i = 0; i < 4; ++i)
                    #pragma unroll
                    for (int j = 0; j < 4; ++j)
                        acc[i][j] = fmaf(ar[i], br[j], acc[i][j]);
            }
            __syncthreads();
        }
        #pragma unroll
        for (int i = 0; i < 4; ++i) {
            float4 o = make_float4(acc[i][0], acc[i][1], acc[i][2], acc[i][3]);
            *(float4*)(Wh + (size_t)(m0 + ty * 4 + i) * (HEADS * HID) + head * HID + tx * 4) = o;
        }
        float4 a1v = *(const float4*)(aheads + head * 2 * HID + tx * 4);
        float4 a2v = *(const float4*)(aheads + head * 2 * HID + HID + tx * 4);
        #pragma unroll
        for (int i = 0; i < 4; ++i) {
            float p1 = acc[i][0] * a1v.x + acc[i][1] * a1v.y + acc[i][2] * a1v.z + acc[i][3] * a1v.w;
            float p2 = acc[i][0] * a2v.x + acc[i][1] * a2v.y + acc[i][2] * a2v.z + acc[i][3] * a2v.w;
            #pragma unroll
            for (int off = 8; off; off >>= 1) {
                p1 += __shfl_down(p1, off, 16);
                p2 += __shfl_down(p2, off, 16);
            }
            if (tx == 0) {
                es[head * NN + m0 + ty * 4 + i] = p1;
                ed[head * NN + m0 + ty * 4 + i] = p2;
            }
        }
    } else {
        int row = bid - GEMM_BLOCKS;
        int* lcnt = (int*)smem;
        const float4* Arow = (const float4*)(A + (size_t)row * NN);
        if (t == 0) *lcnt = 0;
        __syncthreads();
        int* my = nbr + (size_t)row * CAP;
        #pragma unroll
        for (int it = 0; it < NN / 4 / 256; ++it) {
            int idx4 = it * 256 + t;
            float4 v = Arow[idx4];
            int base = idx4 * 4;
            if (v.x != 0.f) { int p = atomicAdd(lcnt, 1); if (p < CAP) my[p] = base; }
            if (v.y != 0.f) { int p = atomicAdd(lcnt, 1); if (p < CAP) my[p] = base + 1; }
            if (v.z != 0.f) { int p = atomicAdd(lcnt, 1); if (p < CAP) my[p] = base + 2; }
            if (v.w != 0.f) { int p = atomicAdd(lcnt, 1); if (p < CAP) my[p] = base + 3; }
        }
        __syncthreads();
        if (t == 0) cnt[row] = *lcnt < CAP ? *lcnt : CAP;
    }
}

// ---------------- k_attn1g2: attention layer 1 (4 waves = 4 heads per row) + fused gemm2/e2 ----------------
__global__ __launch_bounds__(256) void k_attn1g2(const int* __restrict__ nbr, const int* __restrict__ cnt,
                                                 const float* __restrict__ es, const float* __restrict__ ed,
                                                 const float* __restrict__ Wh,
                                                 const float* __restrict__ Wout, const float* __restrict__ aout,
                                                 float* __restrict__ Wh2,
                                                 float* __restrict__ es2, float* __restrict__ ed2) {
    __shared__ int col[CAP];
    __shared__ float att[HEADS][CAP];
    __shared__ float hrow[HEADS * HID];
    __shared__ float part[8][LAT];
    int i = blockIdx.x;
    int t = threadIdx.x, h = t >> 6, l = t & 63;
    int c = cnt[i];
    float hval;
    if (c == 0) {
        float s = 0.f;
        for (int r = 0; r < NN; ++r) s += Wh[(size_t)r * (HEADS * HID) + h * HID + l];
        hval = elu_f(s * (1.0f / NN));
    } else {
        const int* nb = nbr + (size_t)i * CAP;
        float esi = es[h * NN + i];
        float m = -3.0e38f;
        for (int j = l; j < c; j += 64) {
            int cj = nb[j];
            if (h == 0) col[j] = cj;
            float e = lrelu_f(esi + ed[h * NN + cj]);
            att[h][j] = e;
            m = fmaxf(m, e);
        }
        #pragma unroll
        for (int off = 32; off; off >>= 1) m = fmaxf(m, __shfl_down(m, off));
        m = __shfl(m, 0);
        float s = 0.f;
        for (int j = l; j < c; j += 64) {
            float p = __expf(att[h][j] - m);
            att[h][j] = p;
            s += p;
        }
        #pragma unroll
        for (int off = 32; off; off >>= 1) s += __shfl_down(s, off);
        s = __shfl(s, 0);
        __syncthreads();
        float inv = 1.0f / s;
        const float* WhH = Wh + h * HID + l;
        float acc0 = 0.f, acc1 = 0.f, acc2 = 0.f, acc3 = 0.f;
        int j = 0;
        for (; j + 4 <= c; j += 4) {
            acc0 = fmaf(att[h][j + 0], WhH[(size_t)col[j + 0] * (HEADS * HID)], acc0);
            acc1 = fmaf(att[h][j + 1], WhH[(size_t)col[j + 1] * (HEADS * HID)], acc1);
            acc2 = fmaf(att[h][j + 2], WhH[(size_t)col[j + 2] * (HEADS * HID)], acc2);
            acc3 = fmaf(att[h][j + 3], WhH[(size_t)col[j + 3] * (HEADS * HID)], acc3);
        }
        for (; j < c; ++j)
            acc0 = fmaf(att[h][j], WhH[(size_t)col[j] * (HEADS * HID)], acc0);
        hval = elu_f(((acc0 + acc1) + (acc2 + acc3)) * inv);
    }
    hrow[h * HID + l] = hval;
    __syncthreads();
    {
        int half = l >> 5, cc = l & 31;
        int tbase = h * HID + half * 32;
        float p = 0.f;
        #pragma unroll 8
        for (int tt = 0; tt < 32; ++tt)
            p = fmaf(hrow[tbase + tt], Wout[(tbase + tt) * LAT + cc], p);
        part[h * 2 + half][cc] = p;
    }
    __syncthreads();
    if (t < 32) {
        float acc = 0.f;
        #pragma unroll
        for (int w = 0; w < 8; ++w) acc += part[w][t];
        Wh2[(size_t)i * LAT + t] = acc;
        float p1 = acc * aout[t], p2 = acc * aout[LAT + t];
        #pragma unroll
        for (int off = 16; off; off >>= 1) {
            p1 += __shfl_down(p1, off, 32);
            p2 += __shfl_down(p2, off, 32);
        }
        if (t == 0) { es2[i] = p1; ed2[i] = p2; }
    }
}

// ---------------- attention layer 2 -> z (split bf16 out) ----------------
__global__ __launch_bounds__(256) void k_attn2(const int* __restrict__ nbr, const int* __restrict__ cnt,
                                               const float* __restrict__ es2, const float* __restrict__ ed2,
                                               const float* __restrict__ Wh2,
                                               unsigned short* __restrict__ zh, unsigned short* __restrict__ zl) {
    __shared__ float att[4][CAP];
    __shared__ int col[4][CAP];
    int w = threadIdx.x >> 6, l = threadIdx.x & 63;
    int i = blockIdx.x * 4 + w;
    int c = cnt[i];
    if (c == 0) {
        if (l < LAT) {
            float s = 0.f;
            for (int r = 0; r < NN; ++r) s += Wh2[(size_t)r * LAT + l];
            unsigned short hi, lo;
            split_bf16(elu_f(s * (1.0f / NN)), hi, lo);
            zh[(size_t)i * LAT + l] = hi;
            zl[(size_t)i * LAT + l] = lo;
        }
        return;
    }
    float esi = es2[i];
    const int* nb = nbr + (size_t)i * CAP;
    float m = -3.0e38f;
    for (int j = l; j < c; j += 64) {
        int cj = nb[j];
        col[w][j] = cj;
        float e = lrelu_f(esi + ed2[cj]);
        att[w][j] = e;
        m = fmaxf(m, e);
    }
    #pragma unroll
    for (int off = 32; off; off >>= 1) m = fmaxf(m, __shfl_down(m, off));
    m = __shfl(m, 0);
    float s = 0.f;
    for (int j = l; j < c; j += 64) {
        float p = __expf(att[w][j] - m);
        att[w][j] = p;
        s += p;
    }
    #pragma unroll
    for (int off = 32; off; off >>= 1) s += __shfl_down(s, off);
    s = __shfl(s, 0);
    if (l < LAT) {
        float inv = 1.0f / s;
        float acc0 = 0.f, acc1 = 0.f, acc2 = 0.f, acc3 = 0.f;
        int j = 0;
        for (; j + 4 <= c; j += 4) {
            acc0 = fmaf(att[w][j + 0], Wh2[(size_t)col[w][j + 0] * LAT + l], acc0);
            acc1 = fmaf(att[w][j + 1], Wh2[(size_t)col[w][j + 1] * LAT + l], acc1);
            acc2 = fmaf(att[w][j + 2], Wh2[(size_t)col[w][j + 2] * LAT + l], acc2);
            acc3 = fmaf(att[w][j + 3], Wh2[(size_t)col[w][j + 3] * LAT + l], acc3);
        }
        for (; j < c; ++j)
            acc0 = fmaf(att[w][j], Wh2[(size_t)col[w][j] * LAT + l], acc0);
        unsigned short hi, lo;
        split_bf16(elu_f(((acc0 + acc1) + (acc2 + acc3)) * inv), hi, lo);
        zh[(size_t)i * LAT + l] = hi;
        zl[(size_t)i * LAT + l] = lo;
    }
}

// ---------------- out = sigmoid(z @ z^T) via split-bf16 MFMA, no LDS ----------------
// z = zh + zl (bf16 split); z z^T = zh zh^T + zh zl^T + zl zh^T + O(2^-18)
// Each wave: 16-row strip x 64 cols; 4 col-tiles of 16x16x32 MFMA (K = LAT = 32).
__global__ __launch_bounds__(256) void k_zzt(const unsigned short* __restrict__ zh,
                                             const unsigned short* __restrict__ zl,
                                             float* __restrict__ out) {
    int t = threadIdx.x, w = t >> 6, l = t & 63;
    int m0 = blockIdx.y * 64 + w * 16;
    int n0 = blockIdx.x * 64;
    int r = l & 15, kg = (l >> 4) * 8;   // lane row-in-tile, k-group of 8
    bf16x8 ah = *(const bf16x8*)(zh + (size_t)(m0 + r) * LAT + kg);
    bf16x8 al = *(const bf16x8*)(zl + (size_t)(m0 + r) * LAT + kg);
    #pragma unroll
    for (int j = 0; j < 4; ++j) {
        int nb = n0 + j * 16;
        bf16x8 bh = *(const bf16x8*)(zh + (size_t)(nb + r) * LAT + kg);
        bf16x8 bl = *(const bf16x8*)(zl + (size_t)(nb + r) * LAT + kg);
        f32x4 acc = {0.f, 0.f, 0.f, 0.f};
        acc = __builtin_amdgcn_mfma_f32_16x16x32_bf16(ah, bh, acc, 0, 0, 0);
        acc = __builtin_amdgcn_mfma_f32_16x16x32_bf16(ah, bl, acc, 0, 0, 0);
        acc = __builtin_amdgcn_mfma_f32_16x16x32_bf16(al, bh, acc, 0, 0, 0);
        #pragma unroll
        for (int rr = 0; rr < 4; ++rr) {
            int row = m0 + (l >> 4) * 4 + rr;
            int colo = nb + (l & 15);
            out[(size_t)row * NN + colo] = 1.0f / (1.0f + __expf(-acc[rr]));
        }
    }
}

extern "C" void kernel_launch(void* const* d_in, const int* in_sizes, int n_in,
                              void* d_out, int out_size, void* d_ws, size_t ws_size,
                              hipStream_t stream) {
    const float* x      = (const float*)d_in[0];
    const float* A      = (const float*)d_in[1];
    const float* Wheads = (const float*)d_in[2];
    const float* aheads = (const float*)d_in[3];
    const float* Wout   = (const float*)d_in[4];
    const float* aout   = (const float*)d_in[5];
    float* out = (float*)d_out;

    char* ws = (char*)d_ws;
    size_t o = 0;
    auto alloc = [&](size_t bytes) { void* p = ws + o; o += (bytes + 255) & ~(size_t)255; return p; };
    int*   nbr   = (int*)  alloc((size_t)NN * CAP * 4);
    int*   cnt   = (int*)  alloc((size_t)NN * 4);
    float* Wh    = (float*)alloc((size_t)NN * HEADS * HID * 4);
    float* es    = (float*)alloc((size_t)HEADS * NN * 4);
    float* ed    = (float*)alloc((size_t)HEADS * NN * 4);
    float* Wh2   = (float*)alloc((size_t)NN * LAT * 4);
    float* es2   = (float*)alloc((size_t)NN * 4);
    float* ed2   = (float*)alloc((size_t)NN * 4);
    unsigned short* zh = (unsigned short*)alloc((size_t)NN * LAT * 2);
    unsigned short* zl = (unsigned short*)alloc((size_t)NN * LAT * 2);

    k_pre     <<<GEMM_BLOCKS + NN, 256, 0, stream>>>(A, x, Wheads, aheads, nbr, cnt, Wh, es, ed);
    k_attn1g2 <<<NN, 256, 0, stream>>>(nbr, cnt, es, ed, Wh, Wout, aout, Wh2, es2, ed2);
    k_attn2   <<<NN / 4, 256, 0, stream>>>(nbr, cnt, es2, ed2, Wh2, zh, zl);
    k_zzt     <<<dim3(NN / 64, NN / 64), 256, 0, stream>>>(zh, zl, out);
}